// Round 2
// baseline (470.743 us; speedup 1.0000x reference)
//
#include <hip/hip_runtime.h>
#include <hip/hip_bf16.h>
#include <stdint.h>

typedef __bf16 bf16x8 __attribute__((ext_vector_type(8)));
typedef float  f32x4  __attribute__((ext_vector_type(4)));

__device__ __forceinline__ float bf2f(unsigned short u) {
    union { float f; uint32_t i; } v; v.i = ((uint32_t)u) << 16; return v.f;
}
__device__ __forceinline__ unsigned short f2bf(float f) {
    union { float f; uint32_t i; } v; v.f = f;
    uint32_t r = v.i + 0x7FFF + ((v.i >> 16) & 1);
    return (unsigned short)(r >> 16);
}

// ---------------------------------------------------------------------------
// Dtype detector: for bf16 data, bits 14:7 of each 32-bit word are a bf16
// exponent of ~N(0,1) data (concentrated in [100,140]); for fp32 data they
// are uniform mantissa bits (~16% in range). flag=1 -> bf16, flag=0 -> fp32.
// ---------------------------------------------------------------------------
__global__ __launch_bounds__(256) void detect_dtype(
    const uint32_t* __restrict__ x, int* __restrict__ flag)
{
    __shared__ int cnt[256];
    int tid = threadIdx.x;
    uint32_t u = x[tid];
    int e = (u >> 7) & 0xFF;
    cnt[tid] = (e >= 100 && e <= 140) ? 1 : 0;
    __syncthreads();
    for (int s = 128; s > 0; s >>= 1) {
        if (tid < s) cnt[tid] += cnt[tid + s];
        __syncthreads();
    }
    if (tid == 0) flag[0] = (cnt[0] >= 128) ? 1 : 0;
}

// ---------------------------------------------------------------------------
// GEMM:  C[M][N] = A[M][K] * B[N][K]^T   (operands K-contiguous)
// mode 1: fused QKV (N_total=3072, B per 128-col tile); A,B dtype per flag;
//         output scattered bf16 to [b][h][s][64].
// mode 0: single B (Wo); A is bf16 (ws), B dtype per flag; output row-major
//         [M][1024], dtype per flag.
// Block: 256 threads (4 waves, 2x2), tile 128x128, BK=64.
// ---------------------------------------------------------------------------
__global__ __launch_bounds__(256) void gemm_bt(
    const void* __restrict__ A,
    const void* __restrict__ W0,
    const void* __restrict__ W1,
    const void* __restrict__ W2,
    void* __restrict__ O0,
    void* __restrict__ O1,
    void* __restrict__ O2,
    int mode, const int* __restrict__ flag)
{
    const int K = 1024;
    __shared__ __align__(16) unsigned short As[128 * 64];
    __shared__ __align__(16) unsigned short Bs[128 * 64];

    const int isf32 = (flag[0] == 0) ? 1 : 0;
    const int a32 = (mode == 1) ? isf32 : 0;   // mode 0 A comes from ws (bf16)
    const int b32 = isf32;                     // B is always an input weight

    const int tid  = threadIdx.x;
    const int lane = tid & 63;
    const int wid  = tid >> 6;
    const int wm   = wid >> 1;
    const int wn   = wid & 1;
    const int lr   = lane & 15;
    const int quad = lane >> 4;
    const int q8   = quad * 8;

    const int m0  = blockIdx.y * 128;
    const int n0g = blockIdx.x * 128;
    const int sel = n0g >> 10;
    const void* B = (sel == 0) ? W0 : ((sel == 1) ? W1 : W2);
    void* Optr    = (sel == 0) ? O0 : ((sel == 1) ? O1 : O2);
    const int n0  = n0g & 1023;

    f32x4 acc[4][4] = {};

    for (int kk = 0; kk < K; kk += 64) {
        __syncthreads();
        for (int p = 0; p < 4; ++p) {
            int chunk = p * 256 + tid;
            int row = chunk >> 3;
            int c8  = (chunk & 7) * 8;
            // A tile
            if (a32) {
                const float* Af = (const float*)A;
                size_t base = (size_t)(m0 + row) * K + kk + c8;
                float4 f0 = *(const float4*)&Af[base];
                float4 f1 = *(const float4*)&Af[base + 4];
                unsigned short t[8] = { f2bf(f0.x), f2bf(f0.y), f2bf(f0.z), f2bf(f0.w),
                                        f2bf(f1.x), f2bf(f1.y), f2bf(f1.z), f2bf(f1.w) };
                *(uint4*)&As[row * 64 + c8] = *(const uint4*)t;
            } else {
                const unsigned short* Ab = (const unsigned short*)A;
                *(uint4*)&As[row * 64 + c8] =
                    *(const uint4*)&Ab[(size_t)(m0 + row) * K + kk + c8];
            }
            // B tile
            if (b32) {
                const float* Bf = (const float*)B;
                size_t base = (size_t)(n0 + row) * K + kk + c8;
                float4 f0 = *(const float4*)&Bf[base];
                float4 f1 = *(const float4*)&Bf[base + 4];
                unsigned short t[8] = { f2bf(f0.x), f2bf(f0.y), f2bf(f0.z), f2bf(f0.w),
                                        f2bf(f1.x), f2bf(f1.y), f2bf(f1.z), f2bf(f1.w) };
                *(uint4*)&Bs[row * 64 + c8] = *(const uint4*)t;
            } else {
                const unsigned short* Bb = (const unsigned short*)B;
                *(uint4*)&Bs[row * 64 + c8] =
                    *(const uint4*)&Bb[(size_t)(n0 + row) * K + kk + c8];
            }
        }
        __syncthreads();

        for (int ks = 0; ks < 64; ks += 32) {
            bf16x8 af[4], bf[4];
            for (int t = 0; t < 4; ++t) {
                af[t] = *(const bf16x8*)&As[(wm * 64 + t * 16 + lr) * 64 + ks + q8];
                bf[t] = *(const bf16x8*)&Bs[(wn * 64 + t * 16 + lr) * 64 + ks + q8];
            }
            for (int mt = 0; mt < 4; ++mt)
                for (int nt = 0; nt < 4; ++nt)
                    acc[mt][nt] = __builtin_amdgcn_mfma_f32_16x16x32_bf16(
                        af[mt], bf[nt], acc[mt][nt], 0, 0, 0);
        }
    }

    // epilogue: D row = quad*4+reg, col = lane&15
    for (int mt = 0; mt < 4; ++mt) {
        for (int nt = 0; nt < 4; ++nt) {
            for (int r = 0; r < 4; ++r) {
                int m  = m0 + wm * 64 + mt * 16 + quad * 4 + r;
                int nl = n0 + wn * 64 + nt * 16 + lr;
                float val = acc[mt][nt][r];
                if (mode == 0) {
                    if (isf32) ((float*)Optr)[(size_t)m * 1024 + nl] = val;
                    else ((unsigned short*)Optr)[(size_t)m * 1024 + nl] = f2bf(val);
                } else {
                    int b = m >> 11, s = m & 2047;
                    int h = nl >> 6, d = nl & 63;
                    ((unsigned short*)Optr)[((size_t)(b * 16 + h) * 2048 + s) * 64 + d] = f2bf(val);
                }
            }
        }
    }
}

// ---------------------------------------------------------------------------
// RoPE over Q and K in-place (ws buffers, bf16).  Layout [bh=32][s=2048][64].
// Q additionally scaled by 1/sqrt(64) = 0.125 (folds attention scale).
// ---------------------------------------------------------------------------
__global__ __launch_bounds__(256) void rope_kernel(
    unsigned short* __restrict__ Q, unsigned short* __restrict__ Kp)
{
    const int NP = 32 * 2048 * 32;
    int idx = blockIdx.x * 256 + threadIdx.x;
    bool isK = idx >= NP;
    int j = isK ? (idx - NP) : idx;
    unsigned short* p = isK ? Kp : Q;

    int i    = j & 31;
    int srow = j >> 5;
    int s    = srow & 2047;
    int off  = srow * 64 + 2 * i;

    float inv = __expf(-0.2878231366f * (float)i);   // 10000^(-i/32)
    float ang = (float)s * inv;
    float sn, cs;
    sincosf(ang, &sn, &cs);

    float e = bf2f(p[off]);
    float o = bf2f(p[off + 1]);
    float re = e * cs - o * sn;
    float ro = e * sn + o * cs;
    if (!isK) { re *= 0.125f; ro *= 0.125f; }
    p[off]     = f2bf(re);
    p[off + 1] = f2bf(ro);
}

// ---------------------------------------------------------------------------
// Flash attention (causal).  One block = one (b,h) x 64 query rows.
// 4 waves; wave w owns query rows [w*16, w*16+16).
// Q pre-scaled by 0.125, RoPE applied.  Output bf16 to [b][s][h*64+d].
// ---------------------------------------------------------------------------
__global__ __launch_bounds__(256) void attn_kernel(
    const unsigned short* __restrict__ Q,
    const unsigned short* __restrict__ Kp,
    const unsigned short* __restrict__ V,
    unsigned short* __restrict__ AO)
{
    __shared__ __align__(16) unsigned short Qs[64 * 64];
    __shared__ __align__(16) unsigned short Ks[64 * 64];
    __shared__ __align__(16) unsigned short Vt[64 * 64];   // transposed: [d][s_kv]
    __shared__ __align__(16) unsigned short Ps[4 * 16 * 64];

    const int tid  = threadIdx.x;
    const int lane = tid & 63;
    const int w    = tid >> 6;
    const int lr   = lane & 15;
    const int quad = lane >> 4;
    const int q8   = quad * 8;

    const int qb = blockIdx.x;
    const int bh = blockIdx.y;
    const int q0 = qb * 64;

    const unsigned short* Qsrc = Q + ((size_t)bh * 2048 + q0) * 64;
    for (int p = 0; p < 2; ++p) {
        int c = p * 256 + tid;
        *(uint4*)&Qs[c * 8] = *(const uint4*)&Qsrc[c * 8];
    }
    __syncthreads();

    bf16x8 qa[2];
    qa[0] = *(const bf16x8*)&Qs[(w * 16 + lr) * 64 + 0  + q8];
    qa[1] = *(const bf16x8*)&Qs[(w * 16 + lr) * 64 + 32 + q8];

    f32x4 oacc[4] = {};
    float m_i[4], l_i[4];
    for (int r = 0; r < 4; ++r) { m_i[r] = -__builtin_inff(); l_i[r] = 0.0f; }

    for (int kb = 0; kb <= qb; ++kb) {
        __syncthreads();
        const unsigned short* Ksrc = Kp + ((size_t)bh * 2048 + kb * 64) * 64;
        const unsigned short* Vsrc = V  + ((size_t)bh * 2048 + kb * 64) * 64;
        for (int p = 0; p < 2; ++p) {
            int c = p * 256 + tid;
            *(uint4*)&Ks[c * 8] = *(const uint4*)&Ksrc[c * 8];
        }
        for (int p = 0; p < 2; ++p) {
            int c = p * 256 + tid;
            int srow = c >> 3;
            int d0   = (c & 7) * 8;
            uint4 raw = *(const uint4*)&Vsrc[srow * 64 + d0];
            unsigned short tmp[8];
            *(uint4*)tmp = raw;
            for (int jj = 0; jj < 8; ++jj) Vt[(d0 + jj) * 64 + srow] = tmp[jj];
        }
        __syncthreads();

        // S = Q * K^T
        f32x4 sacc[4] = {};
        for (int ks = 0; ks < 2; ++ks) {
            for (int nt = 0; nt < 4; ++nt) {
                bf16x8 bf = *(const bf16x8*)&Ks[(nt * 16 + lr) * 64 + ks * 32 + q8];
                sacc[nt] = __builtin_amdgcn_mfma_f32_16x16x32_bf16(qa[ks], bf, sacc[nt], 0, 0, 0);
            }
        }

        if (kb == qb) {
            for (int nt = 0; nt < 4; ++nt)
                for (int r = 0; r < 4; ++r) {
                    int col = kb * 64 + nt * 16 + lr;
                    int row = q0 + w * 16 + quad * 4 + r;
                    if (col > row) sacc[nt][r] = -__builtin_inff();
                }
        }

        float alpha[4];
        for (int r = 0; r < 4; ++r) {
            float mx = fmaxf(fmaxf(sacc[0][r], sacc[1][r]), fmaxf(sacc[2][r], sacc[3][r]));
            for (int off = 1; off < 16; off <<= 1)
                mx = fmaxf(mx, __shfl_xor(mx, off, 64));
            float mn = fmaxf(m_i[r], mx);
            alpha[r] = __expf(m_i[r] - mn);
            m_i[r] = mn;
        }
        for (int r = 0; r < 4; ++r) {
            float s0 = 0.0f;
            for (int nt = 0; nt < 4; ++nt) {
                float pv = __expf(sacc[nt][r] - m_i[r]);
                s0 += pv;
                Ps[w * 1024 + (quad * 4 + r) * 64 + nt * 16 + lr] = f2bf(pv);
            }
            for (int off = 1; off < 16; off <<= 1)
                s0 += __shfl_xor(s0, off, 64);
            l_i[r] = l_i[r] * alpha[r] + s0;
            for (int nt = 0; nt < 4; ++nt) oacc[nt][r] *= alpha[r];
        }

        // O += P * V (P via wave-private LDS round-trip)
        for (int ks = 0; ks < 2; ++ks) {
            bf16x8 pa = *(const bf16x8*)&Ps[w * 1024 + lr * 64 + ks * 32 + q8];
            for (int nt = 0; nt < 4; ++nt) {
                bf16x8 vb = *(const bf16x8*)&Vt[(nt * 16 + lr) * 64 + ks * 32 + q8];
                oacc[nt] = __builtin_amdgcn_mfma_f32_16x16x32_bf16(pa, vb, oacc[nt], 0, 0, 0);
            }
        }
    }

    const int b = bh >> 4, h = bh & 15;
    for (int r = 0; r < 4; ++r) {
        float inv = 1.0f / l_i[r];
        int s = q0 + w * 16 + quad * 4 + r;
        for (int nt = 0; nt < 4; ++nt) {
            AO[((size_t)b * 2048 + s) * 1024 + h * 64 + nt * 16 + lr] = f2bf(oacc[nt][r] * inv);
        }
    }
}

// ---------------------------------------------------------------------------
extern "C" void kernel_launch(void* const* d_in, const int* in_sizes, int n_in,
                              void* d_out, int out_size, void* d_ws, size_t ws_size,
                              hipStream_t stream)
{
    const void* x  = d_in[0];
    const void* Wq = d_in[1];
    const void* Wk = d_in[2];
    const void* Wv = d_in[3];
    const void* Wo = d_in[4];

    int* flag = (int*)d_ws;
    unsigned short* base = (unsigned short*)d_ws + 8;   // keep 16B alignment
    const size_t QSZ = (size_t)2 * 16 * 2048 * 64;
    unsigned short* q  = base;
    unsigned short* k  = base + QSZ;
    unsigned short* v  = base + 2 * QSZ;
    unsigned short* ao = base + 3 * QSZ;

    // 0) dtype detection (fp32 vs bf16) -> flag
    detect_dtype<<<dim3(1), 256, 0, stream>>>((const uint32_t*)x, flag);
    // 1) fused QKV projection: M=4096, N=3072, K=1024
    gemm_bt<<<dim3(24, 32), 256, 0, stream>>>(x, Wq, Wk, Wv, q, k, v, 1, flag);
    // 2) RoPE on Q (with 0.125 scale) and K
    rope_kernel<<<dim3(16384), 256, 0, stream>>>(q, k);
    // 3) causal flash attention
    attn_kernel<<<dim3(32, 32), 256, 0, stream>>>(q, k, v, ao);
    // 4) output projection: M=4096, N=1024, K=1024
    gemm_bt<<<dim3(8, 32), 256, 0, stream>>>(ao, Wo, Wo, Wo, d_out, d_out, d_out, 0, flag);
}